// Round 9
// baseline (105.867 us; speedup 1.0000x reference)
//
#include <hip/hip_runtime.h>

// ContrastiveLoss on MI355X (gfx950), B=8192, D=128, labels in [0,2048).
// loss = -(1/cnt) sum_{i: P_i>0} [ S_i/P_i - M - ln Z_i ]
//   Z_i = sum_{j != i} exp(sim_ij - M),  sim = E E^T / T,  M = 1/T (valid shift).
//   S_i = (e_i . g_{lab_i} - e_i . e_i) / T  with fp32 class sums g_c.
//   P_i = count[lab_i] - 1.
// R20: R18 base (93.3us best) + two isolated micro-levers:
//      (a) fin1 TLP x2: 1024 blocks x 2 rows/wave (latency-bound; more
//          resident waves = more stall overlap) + inline sdbf (from R19,
//          bit-identical, drops the Ebf gather in fin1);
//      (b) main: 8-deep dependent MFMA chain split into 2 chains (c0:kk0-1,
//          c1:kk2-3, add at end) — halves the per-nt MFMA critical path.
//          +8 VGPR; must stay <=64 (the 8-waves/SIMD step, m69) or occupancy
//          halves (falsifier).
//      R19 post-mortem: killing prep cost +10us in main — fp32 emb (4MB)
//      exactly fills one XCD L2 and thrashes; bf16 Ebf (2MB) stays resident.
//      Ebf + prep restored.
// Retained ledger: R17 8-wave 256x128 tile body (staged B, XOR LDS layout,
//      0 conflicts measured, 16x16x32 MFMA, 32 waves/CU); R18 XCD bijective
//      swizzle (FETCH 8->6MB), class-sum fused as main blocks [1056,1312),
//      zpartR[row][tj2] transposed; plain launch_bounds (R3/R7/R10);
//      separate finalize2 (R14: ticket fence ~9us); no zpartR pre-zero.

#define BATCH 8192
#define DIMK  128
#define INV_T 14.285714285714286f
#define MSUB  14.285714285714286f
#define K1    20.609929155311264f   // INV_T * log2(e)
#define K2    20.609929155311264f   // MSUB  * log2(e)

typedef short bf16x8 __attribute__((ext_vector_type(8)));
typedef float f32x4  __attribute__((ext_vector_type(4)));

__device__ __forceinline__ unsigned short f2bf_rne(float f) {
    unsigned u = __float_as_uint(f);
    u += 0x7FFFu + ((u >> 16) & 1u);
    return (unsigned short)(u >> 16);
}
__device__ __forceinline__ float bf2f(unsigned short b) {
    return __uint_as_float(((unsigned)b) << 16);
}

// ---------------------------------------------------------------------------
// Prep: 1024 blocks: fp32->bf16 cvt (4 elems/thread) + zero zcol (32 KB).
__global__ __launch_bounds__(256) void
prep_kernel(const float* __restrict__ emb, ushort* __restrict__ Ebf,
            float4* __restrict__ zcol4) {
    int i = blockIdx.x * 256 + threadIdx.x;
    if (i < 2048) {                           // zcol: 8192 floats = 2048 float4
        float4 z = {0.f, 0.f, 0.f, 0.f};
        zcol4[i] = z;
    }
    float4 v = ((const float4*)emb)[i];
    ushort4 o;
    o.x = f2bf_rne(v.x); o.y = f2bf_rne(v.y);
    o.z = f2bf_rne(v.z); o.w = f2bf_rne(v.w);
    ((ushort4*)Ebf)[i] = o;
}

// ---------------------------------------------------------------------------
// Main: blocks [0,1056): Z partials over the upper triangle; blocks
// [1056,1312): class sums (8 classes/block, overlapping the tile window).
// Tile blocks: 1056 = 528 macro-tiles x 2 col-halves, 512 threads (8 waves),
// XCD-swizzled (each XCD gets a contiguous run of 132 tt). Macro-tile
// (ti,tj), tj>=ti; block covers rows [ti*256,+256) x cols [tj*256+ch*128,
// +128). B staged once (32 KB), conflict-free XOR layout (measured 0
// conflicts): chunk (col,c) -> unit (col>>4)*256 + c*16 + ((col&15)^c).
// Wave owns 32 rows (afrag[2][4]); per nt, MFMA runs as 2 independent
// 2-deep chains (halved critical path).
// Row partials -> zpartR[row][tj2] (tj2 = tj*2+ch). Col partials (off-diag
// only) -> cpart LDS combine -> atomicAdd zcol[col].
__global__ __launch_bounds__(512) void
contrastive_main(const ushort* __restrict__ Ebf, float* __restrict__ zpartR,
                 float* __restrict__ zcol, const float* __restrict__ emb,
                 const int* __restrict__ labels, float* __restrict__ gsum,
                 int* __restrict__ gcnt) {
    __shared__ __align__(16) ushort Bs[2048 * 8];     // 32 KB (2048 16B units)
    __shared__ float cpart[8][128];                   // 4 KB
    const int tid  = threadIdx.x;
    const int lane = tid & 63;
    const int wid  = tid >> 6;                        // 0..7
    const int quad = lane >> 4;
    const int l16  = lane & 15;

    if (blockIdx.x >= 1056) {
        // ---- class sums: 256 blocks x 8 waves, 1 class per wave ----
        int* labs = (int*)&Bs[0];                     // alias the 32 KB region
#pragma unroll
        for (int it = 0; it < 4; ++it)
            ((int4*)labs)[it * 512 + tid] = ((const int4*)labels)[it * 512 + tid];
        __syncthreads();

        const int c = (blockIdx.x - 1056) * 8 + wid;  // class id [0,2048)
        float2 acc = {0.f, 0.f};
        int cnt = 0;
        int nl = labs[lane];
        for (int j0 = 0; j0 < BATCH; j0 += 64) {
            int cur = nl;
            int nidx = j0 + 64 < BATCH ? j0 + 64 : 0;
            nl = labs[nidx + lane];
            unsigned long long m = __ballot(cur == c);
            cnt += __popcll(m);
            while (m) {
                int j = __ffsll(m) - 1;
                m &= m - 1;
                float2 v = *(const float2*)(emb + (size_t)(j0 + j) * DIMK + lane * 2);
                acc.x += v.x; acc.y += v.y;
            }
        }
        *(float2*)(gsum + (size_t)c * DIMK + lane * 2) = acc;
        if (lane == 0) gcnt[c] = cnt;
        return;
    }

    // ---- tile path ----
    // XCD-aware bijective swizzle: 1056 = 8 * 132; (bid&7) == XCD gets the
    // contiguous tt range [x*132, x*132+132) (R16/R18: FETCH 8->6 MB).
    const int bid = blockIdx.x;
    const int tt  = (bid & 7) * 132 + (bid >> 3);

    // tt -> (ti, tj, ch)
    int b = tt >> 1;
    const int ch = tt & 1;
    int ti = 0;
    while (b >= 32 - ti) { b -= 32 - ti; ++ti; }
    const int tj  = ti + b;
    const int tj2 = tj * 2 + ch;
    const int row_base = ti * 256 + wid * 32;
    const int col_base = tj * 256 + ch * 128;

    // A-fragments for this wave's 32 rows (register-resident), from L2.
    bf16x8 afrag[2][4];
#pragma unroll
    for (int mt = 0; mt < 2; ++mt)
#pragma unroll
        for (int kk = 0; kk < 4; ++kk)
            afrag[mt][kk] = *(const bf16x8*)(Ebf + (size_t)(row_base + mt * 16 + l16) * DIMK
                                             + kk * 32 + quad * 8);

    // Stage 128 cols: 2048 16B chunks; thread t handles chunk f = it*512+t:
    // col = f>>4, c = f&15; global read coalesced (16 lanes = 256B of one col);
    // LDS write at swizzled unit (col>>4)*256 + c*16 + ((col&15)^c).
#pragma unroll
    for (int it = 0; it < 4; ++it) {
        int f   = it * 512 + tid;
        int col = f >> 4;
        int c   = f & 15;
        uint4 v = *(const uint4*)(Ebf + (size_t)(col_base + col) * DIMK + c * 8);
        *(uint4*)&Bs[((col >> 4) * 256 + c * 16 + ((col & 15) ^ c)) * 8] = v;
    }
    __syncthreads();

    float zacc[8];
#pragma unroll
    for (int s = 0; s < 8; ++s) zacc[s] = 0.f;

    for (int nt = 0; nt < 8; ++nt) {
        bf16x8 bfrag[4];
#pragma unroll
        for (int kk = 0; kk < 4; ++kk) {
            const int c2 = kk * 4 + quad;
            bfrag[kk] = *(const bf16x8*)&Bs[(nt * 256 + c2 * 16 + (l16 ^ c2)) * 8];
        }

        float csum = 0.f;
#pragma unroll
        for (int mt = 0; mt < 2; ++mt) {
            // 2 independent 2-deep chains instead of one 4-deep chain.
            f32x4 c0 = {0.f, 0.f, 0.f, 0.f};
            f32x4 c1 = {0.f, 0.f, 0.f, 0.f};
            c0 = __builtin_amdgcn_mfma_f32_16x16x32_bf16(afrag[mt][0], bfrag[0], c0, 0, 0, 0);
            c1 = __builtin_amdgcn_mfma_f32_16x16x32_bf16(afrag[mt][2], bfrag[2], c1, 0, 0, 0);
            c0 = __builtin_amdgcn_mfma_f32_16x16x32_bf16(afrag[mt][1], bfrag[1], c0, 0, 0, 0);
            c1 = __builtin_amdgcn_mfma_f32_16x16x32_bf16(afrag[mt][3], bfrag[3], c1, 0, 0, 0);
#pragma unroll
            for (int r = 0; r < 4; ++r) {
                float e = __builtin_amdgcn_exp2f(__builtin_fmaf(c0[r] + c1[r], K1, -K2));
                zacc[mt * 4 + r] += e;
                csum += e;
            }
        }
        // col partial for col (nt*16 + l16) over this wave's 32 rows
        csum += __shfl_xor(csum, 16, 64);
        csum += __shfl_xor(csum, 32, 64);
        if (quad == 0) cpart[wid][nt * 16 + l16] = csum;
    }

    // Row partials: reduce each row-slot over the 16 lanes sharing the row;
    // store transposed: zpartR[row][tj2] (fin1 reads 256B/row coalesced).
#pragma unroll
    for (int s = 0; s < 8; ++s) {
        float z = zacc[s];
#pragma unroll
        for (int m = 1; m <= 8; m <<= 1) z += __shfl_xor(z, m, 64);
        if (l16 == 0) {
            int row = row_base + (s >> 2) * 16 + quad * 4 + (s & 3);
            zpartR[(size_t)row * 64 + tj2] = z;
        }
    }

    // Col partials: combine the 8 waves, one distributed atomic per column.
    __syncthreads();
    if (ti != tj && tid < 128) {
        float s = cpart[0][tid] + cpart[1][tid] + cpart[2][tid] + cpart[3][tid]
                + cpart[4][tid] + cpart[5][tid] + cpart[6][tid] + cpart[7][tid];
        atomicAdd(&zcol[col_base + tid], s);
    }
}

// ---------------------------------------------------------------------------
// Finalize 1: 1024 blocks x 256 (4 waves); each wave processes 2 rows
// (TLP x2 vs R18). Per row: lane l covers dims 2l,2l+1; Z gather is
// zpartR[r][lane] — 256B contiguous (written only for tj2 >= 2*(r>>8):
// mask, no pre-zeroing); zcol[r] added after the butterfly; bf16 self-dot
// recomputed inline from ev (bit-identical to an Ebf read).
__global__ __launch_bounds__(256) void
finalize1(const float* __restrict__ emb, const int* __restrict__ labels,
          const float* __restrict__ gsum, const int* __restrict__ gcnt,
          const float* __restrict__ zpartR, const float* __restrict__ zcol,
          float* __restrict__ bpart, int* __restrict__ bcnt) {
    __shared__ float sf[4];
    __shared__ int   si[4];
    const int lane = threadIdx.x & 63;
    const int wid  = threadIdx.x >> 6;

    float wsum = 0.f;
    int   wcnt = 0;
#pragma unroll
    for (int it = 0; it < 2; ++it) {
        const int r   = blockIdx.x * 8 + wid * 2 + it;
        const int lab = labels[r];
        const int P   = gcnt[lab] - 1;
        const int tp2 = (r >> 8) * 2;         // first valid tj2 for this row

        float2 ev = *(const float2*)(emb  + (size_t)r   * DIMK + lane * 2);
        float2 gv = *(const float2*)(gsum + (size_t)lab * DIMK + lane * 2);
        float b0 = bf2f(f2bf_rne(ev.x));      // identical to an Ebf read
        float b1 = bf2f(f2bf_rne(ev.y));

        float dotg = ev.x * gv.x + ev.y * gv.y;
        float ssd  = ev.x * ev.x + ev.y * ev.y;
        float sdbf = b0 * b0 + b1 * b1;
        float Z = 0.f;
        if (lane >= tp2) Z = zpartR[(size_t)r * 64 + lane];

#pragma unroll
        for (int m = 1; m <= 32; m <<= 1) {
            dotg += __shfl_xor(dotg, m, 64);
            ssd  += __shfl_xor(ssd,  m, 64);
            sdbf += __shfl_xor(sdbf, m, 64);
            Z    += __shfl_xor(Z,    m, 64);
        }
        Z += zcol[r];                                                // below-diag cols
        Z -= __builtin_amdgcn_exp2f(__builtin_fmaf(sdbf, K1, -K2));  // remove diagonal

        const bool has = (P > 0);
        wsum += has ? ((dotg - ssd) * INV_T / (float)P - MSUB - __logf(Z)) : 0.f;
        wcnt += has ? 1 : 0;
    }

    if (lane == 0) { sf[wid] = wsum; si[wid] = wcnt; }
    __syncthreads();
    if (threadIdx.x == 0) {
        bpart[blockIdx.x] = sf[0] + sf[1] + sf[2] + sf[3];
        bcnt [blockIdx.x] = si[0] + si[1] + si[2] + si[3];
    }
}

// ---------------------------------------------------------------------------
// Finalize 2: reduce 1024 block partials -> scalar loss. 1 block x 256.
__global__ __launch_bounds__(256) void
finalize2(const float* __restrict__ bpart, const int* __restrict__ bcnt,
          float* __restrict__ out) {
    __shared__ float sf[4];
    __shared__ int   si[4];
    const int t = threadIdx.x;
    float v = 0.f; int c = 0;
#pragma unroll
    for (int k = 0; k < 4; ++k) {
        v += bpart[t + k * 256];
        c += bcnt [t + k * 256];
    }
#pragma unroll
    for (int m = 1; m <= 32; m <<= 1) {
        v += __shfl_xor(v, m, 64);
        c += __shfl_xor(c, m, 64);
    }
    if ((t & 63) == 0) { sf[t >> 6] = v; si[t >> 6] = c; }
    __syncthreads();
    if (t == 0) {
        float tot = sf[0] + sf[1] + sf[2] + sf[3];
        int cc = si[0] + si[1] + si[2] + si[3];
        out[0] = -tot / (float)(cc > 0 ? cc : 1);
    }
}

extern "C" void kernel_launch(void* const* d_in, const int* in_sizes, int n_in,
                              void* d_out, int out_size, void* d_ws, size_t ws_size,
                              hipStream_t stream) {
    const float* emb  = (const float*)d_in[0];
    const int* labels = (const int*)d_in[1];
    float* out        = (float*)d_out;

    char* ws = (char*)d_ws;
    ushort* Ebf    = (ushort*)ws;                         // 2 MB  (8192*128*2)
    float*  zpartR = (float*)(ws + (2u << 20));           // 2 MB  ([8192][64] f32)
    float*  zcol   = (float*)(ws + (4u << 20));           // 32 KB (8192*4)
    float*  gsum   = (float*)(ws + (5u << 20));           // 1 MB  (2048*128*4)
    int*    gcnt   = (int*)  (ws + (6u << 20));           // 8 KB
    float*  bpart  = (float*)(ws + (6u << 20) + 8192);    // 4 KB  (1024 f32)
    int*    bcnt   = (int*)  (ws + (6u << 20) + 16384);   // 4 KB  (1024 i32)

    prep_kernel<<<1024, 256, 0, stream>>>(emb, Ebf, (float4*)zcol);
    contrastive_main<<<1312, 512, 0, stream>>>(Ebf, zpartR, zcol,
                                               emb, labels, gsum, gcnt);
    finalize1<<<1024, 256, 0, stream>>>(emb, labels, gsum, gcnt, zpartR, zcol,
                                        bpart, bcnt);
    finalize2<<<1, 256, 0, stream>>>(bpart, bcnt, out);
}

// Round 10
// 91.225 us; speedup vs baseline: 1.1605x; 1.1605x over previous
//
#include <hip/hip_runtime.h>

// ContrastiveLoss on MI355X (gfx950), B=8192, D=128, labels in [0,2048).
// loss = -(1/cnt) sum_{i: P_i>0} [ S_i/P_i - M - ln Z_i ]
//   Z_i = sum_{j != i} exp(sim_ij - M),  sim = E E^T / T,  M = 1/T (valid shift).
//   S_i = (e_i . g_{lab_i} - e_i . e_i) / T  with fp32 class sums g_c.
//   P_i = count[lab_i] - 1.
// R21: surgical revert of R20's falsified lever. R20 post-mortem: MFMA
//      chain-split pushed main to VGPR=68 (>64 step, m69) -> occupancy
//      halved (16.7%) -> main 47us. Twice-measured now (R16, R20): any
//      VGPR increase past an occupancy step loses; TLP > ILP in this
//      latency-bound kernel. Main reverted to R18's single 4-deep chain.
//      KEPT from R20: fin1 TLP x2 (1024 blocks x 2 rows/wave) + inline
//      sdbf (bit-identical; drops fin1's Ebf gather) — this round is the
//      controlled isolation of that lever vs R18's 93.3us.
// Retained ledger: R17 8-wave 256x128 tile body (staged B, XOR LDS layout,
//      0 conflicts measured, 16x16x32 MFMA); R18 XCD bijective swizzle
//      (FETCH 8->6MB at 256t; ~neutral at 512t per R20, kept as cheap),
//      class-sum fused as main blocks [1056,1312), zpartR[row][tj2]
//      transposed (coalesced fin1 gather); bf16 Ebf intermediate is
//      L2-residency-critical (R19: fp32 direct = +10us); plain
//      launch_bounds (R3/R7/R10: min-waves pin spills); separate finalize2
//      (R14: ticket fence ~9us); no zpartR pre-zero (fin1 masks).

#define BATCH 8192
#define DIMK  128
#define INV_T 14.285714285714286f
#define MSUB  14.285714285714286f
#define K1    20.609929155311264f   // INV_T * log2(e)
#define K2    20.609929155311264f   // MSUB  * log2(e)

typedef short bf16x8 __attribute__((ext_vector_type(8)));
typedef float f32x4  __attribute__((ext_vector_type(4)));

__device__ __forceinline__ unsigned short f2bf_rne(float f) {
    unsigned u = __float_as_uint(f);
    u += 0x7FFFu + ((u >> 16) & 1u);
    return (unsigned short)(u >> 16);
}
__device__ __forceinline__ float bf2f(unsigned short b) {
    return __uint_as_float(((unsigned)b) << 16);
}

// ---------------------------------------------------------------------------
// Prep: 1024 blocks: fp32->bf16 cvt (4 elems/thread) + zero zcol (32 KB).
__global__ __launch_bounds__(256) void
prep_kernel(const float* __restrict__ emb, ushort* __restrict__ Ebf,
            float4* __restrict__ zcol4) {
    int i = blockIdx.x * 256 + threadIdx.x;
    if (i < 2048) {                           // zcol: 8192 floats = 2048 float4
        float4 z = {0.f, 0.f, 0.f, 0.f};
        zcol4[i] = z;
    }
    float4 v = ((const float4*)emb)[i];
    ushort4 o;
    o.x = f2bf_rne(v.x); o.y = f2bf_rne(v.y);
    o.z = f2bf_rne(v.z); o.w = f2bf_rne(v.w);
    ((ushort4*)Ebf)[i] = o;
}

// ---------------------------------------------------------------------------
// Main: blocks [0,1056): Z partials over the upper triangle; blocks
// [1056,1312): class sums (8 classes/block, overlapping the tile window).
// Tile blocks: 1056 = 528 macro-tiles x 2 col-halves, 512 threads (8 waves),
// XCD-swizzled (each XCD gets a contiguous run of 132 tt). Macro-tile
// (ti,tj), tj>=ti; block covers rows [ti*256,+256) x cols [tj*256+ch*128,
// +128). B staged once (32 KB), conflict-free XOR layout (measured 0
// conflicts): chunk (col,c) -> unit (col>>4)*256 + c*16 + ((col&15)^c).
// Wave owns 32 rows (afrag[2][4]); single 4-deep MFMA chain per mt (R18 —
// the R20 chain-split crossed the 64-VGPR occupancy step and regressed).
// Row partials -> zpartR[row][tj2] (tj2 = tj*2+ch). Col partials (off-diag
// only) -> cpart LDS combine -> atomicAdd zcol[col].
__global__ __launch_bounds__(512) void
contrastive_main(const ushort* __restrict__ Ebf, float* __restrict__ zpartR,
                 float* __restrict__ zcol, const float* __restrict__ emb,
                 const int* __restrict__ labels, float* __restrict__ gsum,
                 int* __restrict__ gcnt) {
    __shared__ __align__(16) ushort Bs[2048 * 8];     // 32 KB (2048 16B units)
    __shared__ float cpart[8][128];                   // 4 KB
    const int tid  = threadIdx.x;
    const int lane = tid & 63;
    const int wid  = tid >> 6;                        // 0..7
    const int quad = lane >> 4;
    const int l16  = lane & 15;

    if (blockIdx.x >= 1056) {
        // ---- class sums: 256 blocks x 8 waves, 1 class per wave ----
        int* labs = (int*)&Bs[0];                     // alias the 32 KB region
#pragma unroll
        for (int it = 0; it < 4; ++it)
            ((int4*)labs)[it * 512 + tid] = ((const int4*)labels)[it * 512 + tid];
        __syncthreads();

        const int c = (blockIdx.x - 1056) * 8 + wid;  // class id [0,2048)
        float2 acc = {0.f, 0.f};
        int cnt = 0;
        int nl = labs[lane];
        for (int j0 = 0; j0 < BATCH; j0 += 64) {
            int cur = nl;
            int nidx = j0 + 64 < BATCH ? j0 + 64 : 0;
            nl = labs[nidx + lane];
            unsigned long long m = __ballot(cur == c);
            cnt += __popcll(m);
            while (m) {
                int j = __ffsll(m) - 1;
                m &= m - 1;
                float2 v = *(const float2*)(emb + (size_t)(j0 + j) * DIMK + lane * 2);
                acc.x += v.x; acc.y += v.y;
            }
        }
        *(float2*)(gsum + (size_t)c * DIMK + lane * 2) = acc;
        if (lane == 0) gcnt[c] = cnt;
        return;
    }

    // ---- tile path ----
    // XCD-aware bijective swizzle: 1056 = 8 * 132; (bid&7) == XCD gets the
    // contiguous tt range [x*132, x*132+132).
    const int bid = blockIdx.x;
    const int tt  = (bid & 7) * 132 + (bid >> 3);

    // tt -> (ti, tj, ch)
    int b = tt >> 1;
    const int ch = tt & 1;
    int ti = 0;
    while (b >= 32 - ti) { b -= 32 - ti; ++ti; }
    const int tj  = ti + b;
    const int tj2 = tj * 2 + ch;
    const int row_base = ti * 256 + wid * 32;
    const int col_base = tj * 256 + ch * 128;

    // A-fragments for this wave's 32 rows (register-resident), from L2.
    bf16x8 afrag[2][4];
#pragma unroll
    for (int mt = 0; mt < 2; ++mt)
#pragma unroll
        for (int kk = 0; kk < 4; ++kk)
            afrag[mt][kk] = *(const bf16x8*)(Ebf + (size_t)(row_base + mt * 16 + l16) * DIMK
                                             + kk * 32 + quad * 8);

    // Stage 128 cols: 2048 16B chunks; thread t handles chunk f = it*512+t:
    // col = f>>4, c = f&15; global read coalesced (16 lanes = 256B of one col);
    // LDS write at swizzled unit (col>>4)*256 + c*16 + ((col&15)^c).
#pragma unroll
    for (int it = 0; it < 4; ++it) {
        int f   = it * 512 + tid;
        int col = f >> 4;
        int c   = f & 15;
        uint4 v = *(const uint4*)(Ebf + (size_t)(col_base + col) * DIMK + c * 8);
        *(uint4*)&Bs[((col >> 4) * 256 + c * 16 + ((col & 15) ^ c)) * 8] = v;
    }
    __syncthreads();

    float zacc[8];
#pragma unroll
    for (int s = 0; s < 8; ++s) zacc[s] = 0.f;

    for (int nt = 0; nt < 8; ++nt) {
        bf16x8 bfrag[4];
#pragma unroll
        for (int kk = 0; kk < 4; ++kk) {
            const int c2 = kk * 4 + quad;
            bfrag[kk] = *(const bf16x8*)&Bs[(nt * 256 + c2 * 16 + (l16 ^ c2)) * 8];
        }

        float csum = 0.f;
#pragma unroll
        for (int mt = 0; mt < 2; ++mt) {
            f32x4 c = {0.f, 0.f, 0.f, 0.f};
#pragma unroll
            for (int kk = 0; kk < 4; ++kk)
                c = __builtin_amdgcn_mfma_f32_16x16x32_bf16(afrag[mt][kk], bfrag[kk], c, 0, 0, 0);
#pragma unroll
            for (int r = 0; r < 4; ++r) {
                float e = __builtin_amdgcn_exp2f(__builtin_fmaf(c[r], K1, -K2));
                zacc[mt * 4 + r] += e;
                csum += e;
            }
        }
        // col partial for col (nt*16 + l16) over this wave's 32 rows
        csum += __shfl_xor(csum, 16, 64);
        csum += __shfl_xor(csum, 32, 64);
        if (quad == 0) cpart[wid][nt * 16 + l16] = csum;
    }

    // Row partials: reduce each row-slot over the 16 lanes sharing the row;
    // store transposed: zpartR[row][tj2] (fin1 reads 256B/row coalesced).
#pragma unroll
    for (int s = 0; s < 8; ++s) {
        float z = zacc[s];
#pragma unroll
        for (int m = 1; m <= 8; m <<= 1) z += __shfl_xor(z, m, 64);
        if (l16 == 0) {
            int row = row_base + (s >> 2) * 16 + quad * 4 + (s & 3);
            zpartR[(size_t)row * 64 + tj2] = z;
        }
    }

    // Col partials: combine the 8 waves, one distributed atomic per column.
    __syncthreads();
    if (ti != tj && tid < 128) {
        float s = cpart[0][tid] + cpart[1][tid] + cpart[2][tid] + cpart[3][tid]
                + cpart[4][tid] + cpart[5][tid] + cpart[6][tid] + cpart[7][tid];
        atomicAdd(&zcol[col_base + tid], s);
    }
}

// ---------------------------------------------------------------------------
// Finalize 1: 1024 blocks x 256 (4 waves); each wave processes 2 rows
// (TLP x2 vs R18). Per row: lane l covers dims 2l,2l+1; Z gather is
// zpartR[r][lane] — 256B contiguous (written only for tj2 >= 2*(r>>8):
// mask, no pre-zeroing); zcol[r] added after the butterfly; bf16 self-dot
// recomputed inline from ev (bit-identical to an Ebf read).
__global__ __launch_bounds__(256) void
finalize1(const float* __restrict__ emb, const int* __restrict__ labels,
          const float* __restrict__ gsum, const int* __restrict__ gcnt,
          const float* __restrict__ zpartR, const float* __restrict__ zcol,
          float* __restrict__ bpart, int* __restrict__ bcnt) {
    __shared__ float sf[4];
    __shared__ int   si[4];
    const int lane = threadIdx.x & 63;
    const int wid  = threadIdx.x >> 6;

    float wsum = 0.f;
    int   wcnt = 0;
#pragma unroll
    for (int it = 0; it < 2; ++it) {
        const int r   = blockIdx.x * 8 + wid * 2 + it;
        const int lab = labels[r];
        const int P   = gcnt[lab] - 1;
        const int tp2 = (r >> 8) * 2;         // first valid tj2 for this row

        float2 ev = *(const float2*)(emb  + (size_t)r   * DIMK + lane * 2);
        float2 gv = *(const float2*)(gsum + (size_t)lab * DIMK + lane * 2);
        float b0 = bf2f(f2bf_rne(ev.x));      // identical to an Ebf read
        float b1 = bf2f(f2bf_rne(ev.y));

        float dotg = ev.x * gv.x + ev.y * gv.y;
        float ssd  = ev.x * ev.x + ev.y * ev.y;
        float sdbf = b0 * b0 + b1 * b1;
        float Z = 0.f;
        if (lane >= tp2) Z = zpartR[(size_t)r * 64 + lane];

#pragma unroll
        for (int m = 1; m <= 32; m <<= 1) {
            dotg += __shfl_xor(dotg, m, 64);
            ssd  += __shfl_xor(ssd,  m, 64);
            sdbf += __shfl_xor(sdbf, m, 64);
            Z    += __shfl_xor(Z,    m, 64);
        }
        Z += zcol[r];                                                // below-diag cols
        Z -= __builtin_amdgcn_exp2f(__builtin_fmaf(sdbf, K1, -K2));  // remove diagonal

        const bool has = (P > 0);
        wsum += has ? ((dotg - ssd) * INV_T / (float)P - MSUB - __logf(Z)) : 0.f;
        wcnt += has ? 1 : 0;
    }

    if (lane == 0) { sf[wid] = wsum; si[wid] = wcnt; }
    __syncthreads();
    if (threadIdx.x == 0) {
        bpart[blockIdx.x] = sf[0] + sf[1] + sf[2] + sf[3];
        bcnt [blockIdx.x] = si[0] + si[1] + si[2] + si[3];
    }
}

// ---------------------------------------------------------------------------
// Finalize 2: reduce 1024 block partials -> scalar loss. 1 block x 256.
__global__ __launch_bounds__(256) void
finalize2(const float* __restrict__ bpart, const int* __restrict__ bcnt,
          float* __restrict__ out) {
    __shared__ float sf[4];
    __shared__ int   si[4];
    const int t = threadIdx.x;
    float v = 0.f; int c = 0;
#pragma unroll
    for (int k = 0; k < 4; ++k) {
        v += bpart[t + k * 256];
        c += bcnt [t + k * 256];
    }
#pragma unroll
    for (int m = 1; m <= 32; m <<= 1) {
        v += __shfl_xor(v, m, 64);
        c += __shfl_xor(c, m, 64);
    }
    if ((t & 63) == 0) { sf[t >> 6] = v; si[t >> 6] = c; }
    __syncthreads();
    if (t == 0) {
        float tot = sf[0] + sf[1] + sf[2] + sf[3];
        int cc = si[0] + si[1] + si[2] + si[3];
        out[0] = -tot / (float)(cc > 0 ? cc : 1);
    }
}

extern "C" void kernel_launch(void* const* d_in, const int* in_sizes, int n_in,
                              void* d_out, int out_size, void* d_ws, size_t ws_size,
                              hipStream_t stream) {
    const float* emb  = (const float*)d_in[0];
    const int* labels = (const int*)d_in[1];
    float* out        = (float*)d_out;

    char* ws = (char*)d_ws;
    ushort* Ebf    = (ushort*)ws;                         // 2 MB  (8192*128*2)
    float*  zpartR = (float*)(ws + (2u << 20));           // 2 MB  ([8192][64] f32)
    float*  zcol   = (float*)(ws + (4u << 20));           // 32 KB (8192*4)
    float*  gsum   = (float*)(ws + (5u << 20));           // 1 MB  (2048*128*4)
    int*    gcnt   = (int*)  (ws + (6u << 20));           // 8 KB
    float*  bpart  = (float*)(ws + (6u << 20) + 8192);    // 4 KB  (1024 f32)
    int*    bcnt   = (int*)  (ws + (6u << 20) + 16384);   // 4 KB  (1024 i32)

    prep_kernel<<<1024, 256, 0, stream>>>(emb, Ebf, (float4*)zcol);
    contrastive_main<<<1312, 512, 0, stream>>>(Ebf, zpartR, zcol,
                                               emb, labels, gsum, gcnt);
    finalize1<<<1024, 256, 0, stream>>>(emb, labels, gsum, gcnt, zpartR, zcol,
                                        bpart, bcnt);
    finalize2<<<1, 256, 0, stream>>>(bpart, bcnt, out);
}